// Round 14
// baseline (247.989 us; speedup 1.0000x reference)
//
#include <hip/hip_runtime.h>
#include <hip/hip_bf16.h>
#include <math.h>

typedef __attribute__((ext_vector_type(8))) short short8;
typedef __attribute__((ext_vector_type(4))) short short4v;
typedef __attribute__((ext_vector_type(4))) float f32x4;

static __device__ __forceinline__ short f2bf(float f) {
  union { float f; unsigned u; } x;
  x.f = f;
  unsigned r = x.u + 0x7fffu + ((x.u >> 16) & 1u);
  return (short)(r >> 16);
}

#define GLD16(g, l)                                                   \
  __builtin_amdgcn_global_load_lds(                                   \
      (const __attribute__((address_space(1))) void*)(g),             \
      (__attribute__((address_space(3))) void*)(l), 16, 0, 0)
#define BAR() asm volatile("s_barrier" ::: "memory")
#define VM0() asm volatile("s_waitcnt vmcnt(0)" ::: "memory")

// fused cast: x, Wq, Wk, Wv -> bf16 in one launch
__global__ __launch_bounds__(256) void cvt_all(
    const float* __restrict__ x, const float* __restrict__ wq,
    const float* __restrict__ wk, const float* __restrict__ wv,
    short* __restrict__ xb, short* __restrict__ wqb,
    short* __restrict__ wkb, short* __restrict__ wvb, int n0, int n1) {
  int i = blockIdx.x * 256 + threadIdx.x;
  const float* src; short* dst; int off;
  if (i < n0) { src = x; dst = xb; off = i; }
  else if (i < n0 + n1) { src = wq; dst = wqb; off = i - n0; }
  else if (i < n0 + 2 * n1) { src = wk; dst = wkb; off = i - n0 - n1; }
  else if (i < n0 + 3 * n1) { src = wv; dst = wvb; off = i - n0 - 2 * n1; }
  else return;
  const float4* p = (const float4*)src + (size_t)off * 2;
  float4 a = p[0], b = p[1];
  short8 o;
  o[0] = f2bf(a.x); o[1] = f2bf(a.y); o[2] = f2bf(a.z); o[3] = f2bf(a.w);
  o[4] = f2bf(b.x); o[5] = f2bf(b.y); o[6] = f2bf(b.z); o[7] = f2bf(b.w);
  *((short8*)dst + off) = o;
}

// ---------------------------------------------------------------------------
// C = A * B^T, bf16 MFMA 16x16x32. BM=256, BN={128,64}, BK=32, 256 threads =
// 4 waves stacked in M; wave tile 64xBN (M_rep=4, N_rep=BN/16). R13 structure
// (proven best) + K-loop UNROLLED x3 with static buffer names: no pointer
// rotation, all LDS/stage addresses are compile-time offsets from bases
// advanced once per 3-tile group (cuts the ~37 VALU-inst/K-tile addr math).
// vmcnt(LPT) per sub (LPT = 4 + BN/64 loads/tile); tails for (NT-2)%3 in
// {0,2} (NT=32 / NT=64). Both-sides XOR swizzle (slot ^= (row>>1)&3),
// bijective XCD block swizzle. PV uses BN=64 -> 512 blocks (2/CU occupancy).
// MODE 2: C fp32 = acc*scale + rel_bias[gc-gr+ml-1] (scores)
// MODE 3: C fp32 = acc (PV)
// MODE 4: fused QKV: 1024-col slice 0 -> Q, 1 -> K, 2 -> V (ALL row-major)
// ---------------------------------------------------------------------------
template <int MODE, int BN>
__global__ __launch_bounds__(256, 2) void gemm_u3(
    const short* __restrict__ A, const short* __restrict__ Bt,
    void* __restrict__ C0, void* __restrict__ C1, void* __restrict__ C2,
    const float* __restrict__ rel_bias,
    int N, int K, long aZ, long bZ, long cZ, int Cdim, float scale, int ml) {
  constexpr int NREP = BN / 16;         // 8 or 4
  constexpr int BCH = BN / 64;          // B 64-row chunks: 2 or 1
  __shared__ short sA[3][256 * 32];
  __shared__ short sB[3][BN * 32];
  const int tid = threadIdx.x, lane = tid & 63, wid = tid >> 6;

  // bijective XCD swizzle over the flat workgroup id
  const int gx = gridDim.x, gy = gridDim.y;
  const int nwg = gx * gy * (int)gridDim.z;
  const int f = ((int)blockIdx.z * gy + (int)blockIdx.y) * gx + (int)blockIdx.x;
  const int qq = nwg >> 3, rr = nwg & 7;
  const int xcd = f & 7, pos = f >> 3;
  const int lg = (xcd < rr ? xcd * (qq + 1) : rr * (qq + 1) + (xcd - rr) * qq) + pos;
  const int z = lg / (gx * gy);
  const int rem = lg - z * (gx * gy);
  const int bx = rem / gy, by = rem - bx * gy;  // by fastest: A-panel reuse

  const short* Az = A + (size_t)z * aZ;
  const short* Bz = Bt + (size_t)z * bZ;
  const int brow = bx * 256, bcol = by * BN;
  const int lrow = lane & 15, kg = lane >> 4;

  // staging: chunk c covers rows c*64..+63; thread -> row tid>>2, slot tid&3
  const int t4 = tid >> 2;
  const int logslot = (tid & 3) ^ ((tid >> 3) & 3);  // pre-swizzled src slot
  const short* aS[4];
#pragma unroll
  for (int c = 0; c < 4; ++c)
    aS[c] = Az + (size_t)(brow + c * 64 + t4) * K + logslot * 8;
  const short* bS[BCH];
#pragma unroll
  for (int c = 0; c < BCH; ++c)
    bS[c] = Bz + (size_t)(bcol + c * 64 + t4) * K + logslot * 8;
  const int dW = wid * 512;  // wave-uniform LDS dest offset within chunk

  // ds_read: physical slot = kg ^ ((row>>1)&3); (row>>1)&3 == (lrow>>1)&3
  const int kOff = (kg ^ ((lrow >> 1) & 3)) * 8;
  const int aBase = (wid * 64 + lrow) * 32 + kOff;  // + m*512
  const int bBase = lrow * 32 + kOff;               // + n*512

  short8 a[4], b[NREP];
  f32x4 acc[4][NREP] = {};

  short* const pa0 = &sA[0][0];
  short* const pa1 = &sA[1][0];
  short* const pa2 = &sA[2][0];
  short* const pb0 = &sB[0][0];
  short* const pb1 = &sB[1][0];
  short* const pb2 = &sB[2][0];

#define STG(PA, PB, OFF)                                             \
  do {                                                               \
    GLD16(aS[0] + (OFF), (PA) + 0 * 2048 + dW);                      \
    GLD16(aS[1] + (OFF), (PA) + 1 * 2048 + dW);                      \
    GLD16(aS[2] + (OFF), (PA) + 2 * 2048 + dW);                      \
    GLD16(aS[3] + (OFF), (PA) + 3 * 2048 + dW);                      \
    GLD16(bS[0] + (OFF), (PB) + 0 * 2048 + dW);                      \
    if constexpr (BCH == 2) GLD16(bS[1] + (OFF), (PB) + 2048 + dW);  \
  } while (0)
#define RD(PA, PB)                                                  \
  do {                                                              \
    _Pragma("unroll") for (int m = 0; m < 4; ++m)                   \
        a[m] = *(const short8*)&(PA)[aBase + m * 512];              \
    _Pragma("unroll") for (int n = 0; n < NREP; ++n)                \
        b[n] = *(const short8*)&(PB)[bBase + n * 512];              \
  } while (0)
#define MFMA_ALL()                                                            \
  do {                                                                        \
    __builtin_amdgcn_s_setprio(1);                                            \
    _Pragma("unroll") for (int m = 0; m < 4; ++m)                             \
        _Pragma("unroll") for (int n = 0; n < NREP; ++n)                      \
            acc[m][n] = __builtin_amdgcn_mfma_f32_16x16x32_bf16(              \
                a[m], b[n], acc[m][n], 0, 0, 0);                              \
    __builtin_amdgcn_s_setprio(0);                                            \
  } while (0)
#define VM_LPT()                                                    \
  do {                                                              \
    if constexpr (BCH == 2)                                         \
      asm volatile("s_waitcnt vmcnt(6)" ::: "memory");              \
    else                                                            \
      asm volatile("s_waitcnt vmcnt(5)" ::: "memory");              \
  } while (0)

  // prologue: tiles 0 (buf0) and 1 (buf1); 2*LPT loads outstanding
  STG(pa0, pb0, 0);
  STG(pa1, pb1, 32);

  const int NT = K >> 5;          // K/32 tiles: 32 or 64 here
  const int G = (NT - 2) / 3;     // full 3-tile groups
  for (int g = 0; g < G; ++g) {
    // sub0: read tile 3g (buf0); stage 3g+2 -> buf2
    VM_LPT(); BAR();
    RD(pa0, pb0);
    STG(pa2, pb2, 64);
    MFMA_ALL();
    // sub1: read 3g+1 (buf1); stage 3g+3 -> buf0 (reads done pre-barrier)
    VM_LPT(); BAR();
    RD(pa1, pb1);
    STG(pa0, pb0, 96);
    MFMA_ALL();
    // sub2: read 3g+2 (buf2); stage 3g+4 -> buf1
    VM_LPT(); BAR();
    RD(pa2, pb2);
    STG(pa1, pb1, 128);
    MFMA_ALL();
    // advance group base by 3 tiles
#pragma unroll
    for (int c = 0; c < 4; ++c) aS[c] += 96;
#pragma unroll
    for (int c = 0; c < BCH; ++c) bS[c] += 96;
  }
  if ((NT - 2) % 3 == 2) {  // NT=64: tiles NT-4..NT-1 remain (60..63)
    VM_LPT(); BAR();
    RD(pa0, pb0);             // tile NT-4 (base+0)
    STG(pa2, pb2, 64);        // tile NT-2 -> buf2
    MFMA_ALL();
    VM_LPT(); BAR();
    RD(pa1, pb1);             // tile NT-3
    STG(pa0, pb0, 96);        // tile NT-1 -> buf0
    MFMA_ALL();
    VM_LPT(); BAR();
    RD(pa2, pb2);             // tile NT-2
    MFMA_ALL();
    VM0(); BAR();
    RD(pa0, pb0);             // tile NT-1
    MFMA_ALL();
  } else {                  // NT=32: tiles NT-2, NT-1 remain (30, 31)
    VM_LPT(); BAR();
    RD(pa0, pb0);
    MFMA_ALL();
    VM0(); BAR();
    RD(pa1, pb1);
    MFMA_ALL();
  }

  // epilogue
#pragma unroll
  for (int m = 0; m < 4; ++m) {
#pragma unroll
    for (int n = 0; n < NREP; ++n) {
#pragma unroll
      for (int r = 0; r < 4; ++r) {
        float v = acc[m][n][r];
        int gr = brow + wid * 64 + m * 16 + kg * 4 + r;
        int gc = bcol + n * 16 + lrow;
        if constexpr (MODE == 2) {
          int idx = gc - gr + (ml - 1);
          idx = min(max(idx, 0), 2 * ml - 2);
          ((float*)C0 + (size_t)z * cZ)[(size_t)gr * N + gc] =
              v * scale + rel_bias[idx];
        } else if constexpr (MODE == 3) {
          ((float*)C0 + (size_t)z * cZ)[(size_t)gr * N + gc] = v;
        } else {  // MODE 4: fused QKV, 1024-col slices, ALL row-major
          int s = gc >> 10, cc = gc & 1023;
          short* dst = (s == 0) ? (short*)C0 : (s == 1) ? (short*)C1 : (short*)C2;
          dst[(size_t)gr * 1024 + cc] = f2bf(v);
        }
      }
    }
  }
#undef STG
#undef RD
#undef MFMA_ALL
#undef VM_LPT
}

// 64x64 LDS tile transpose: vin[b][c][e] (row-major [Cd][E]) -> vout[b][e][c]
__global__ __launch_bounds__(256) void transpose_v(const short* __restrict__ vin,
                                                   short* __restrict__ vout,
                                                   int Cd, int E) {
  __shared__ short t[64][72];
  const int c0 = blockIdx.x * 64, e0 = blockIdx.y * 64, b = blockIdx.z;
  const int tid = threadIdx.x;
  const int cr = tid >> 2;             // 0..63: input row within tile
  const int ec = (tid & 3) * 16;       // input col chunk
  const short* src = vin + ((size_t)b * Cd + c0 + cr) * E + e0 + ec;
  short8 v0 = *(const short8*)src;
  short8 v1 = *(const short8*)(src + 8);
#pragma unroll
  for (int j = 0; j < 8; ++j) t[ec + j][cr] = v0[j];
#pragma unroll
  for (int j = 0; j < 8; ++j) t[ec + 8 + j][cr] = v1[j];
  __syncthreads();
  const int er = tid >> 2;             // output row (e-dim)
  const int cc = (tid & 3) * 16;       // output col chunk (c-dim)
  short* dst = vout + ((size_t)b * E + e0 + er) * Cd + c0 + cc;
  *(short8*)dst = *(const short8*)&t[er][cc];
  *(short8*)(dst + 8) = *(const short8*)&t[er][cc + 8];
}

// Row softmax in place (rows of 2048) + bf16 copy for the PV GEMM.
__global__ __launch_bounds__(256) void softmax_rows(float* __restrict__ w,
                                                    short* __restrict__ wb, int Cd) {
  const size_t row = blockIdx.x;
  float4* p = (float4*)(w + row * (size_t)Cd);
  const int tid = threadIdx.x;
  float4 v0 = p[tid];
  float4 v1 = p[tid + 256];
  float mx = fmaxf(fmaxf(fmaxf(v0.x, v0.y), fmaxf(v0.z, v0.w)),
                   fmaxf(fmaxf(v1.x, v1.y), fmaxf(v1.z, v1.w)));
#pragma unroll
  for (int o = 32; o; o >>= 1) mx = fmaxf(mx, __shfl_xor(mx, o));
  __shared__ float red[8];
  const int wv = tid >> 6;
  if ((tid & 63) == 0) red[wv] = mx;
  __syncthreads();
  mx = fmaxf(fmaxf(red[0], red[1]), fmaxf(red[2], red[3]));
  v0.x = __expf(v0.x - mx); v0.y = __expf(v0.y - mx);
  v0.z = __expf(v0.z - mx); v0.w = __expf(v0.w - mx);
  v1.x = __expf(v1.x - mx); v1.y = __expf(v1.y - mx);
  v1.z = __expf(v1.z - mx); v1.w = __expf(v1.w - mx);
  float s = v0.x + v0.y + v0.z + v0.w + v1.x + v1.y + v1.z + v1.w;
#pragma unroll
  for (int o = 32; o; o >>= 1) s += __shfl_xor(s, o);
  if ((tid & 63) == 0) red[4 + wv] = s;
  __syncthreads();
  s = red[4] + red[5] + red[6] + red[7];
  float inv = 1.0f / s;
  v0.x *= inv; v0.y *= inv; v0.z *= inv; v0.w *= inv;
  v1.x *= inv; v1.y *= inv; v1.z *= inv; v1.w *= inv;
  p[tid] = v0;
  p[tid + 256] = v1;
  short4v b0, b1;
  b0[0] = f2bf(v0.x); b0[1] = f2bf(v0.y); b0[2] = f2bf(v0.z); b0[3] = f2bf(v0.w);
  b1[0] = f2bf(v1.x); b1[1] = f2bf(v1.y); b1[2] = f2bf(v1.z); b1[3] = f2bf(v1.w);
  short* wrow = wb + row * (size_t)Cd;
  *(short4v*)&wrow[tid * 4] = b0;
  *(short4v*)&wrow[1024 + tid * 4] = b1;
}

extern "C" void kernel_launch(void* const* d_in, const int* in_sizes, int n_in,
                              void* d_out, int out_size, void* d_ws, size_t ws_size,
                              hipStream_t stream) {
  const float* x = (const float*)d_in[0];
  const float* Wq = (const float*)d_in[1];
  const float* Wk = (const float*)d_in[2];
  const float* Wv = (const float*)d_in[3];
  const float* rb = (const float*)d_in[4];

  const int E = 1024;
  const int Mt = in_sizes[0] / E;           // B*C = 8192
  const int Cd = out_size / Mt - E;         // 2048
  const int B = Mt / Cd;                    // 4
  const int ml = (in_sizes[4] + 1) / 2;     // max_len = 2048
  const float scale = 1.0f / sqrtf((float)E);

  // workspace layout (bf16 = short), 70 MB
  short* xb = (short*)d_ws;                 // Mt*E (dead after QKV -> Vt)
  short* wqb = xb + (size_t)Mt * E;         // E*E x3
  short* wkb = wqb + (size_t)E * E;
  short* wvb = wkb + (size_t)E * E;
  short* Qb = wvb + (size_t)E * E;          // Mt*E
  short* Kb = Qb + (size_t)Mt * E;          // Mt*E
  short* Vrow = Kb + (size_t)Mt * E;        // Mt*E (V row-major)
  short* Vt = xb;                           // B*E*Cd = Mt*E (reuse xb)
  short* wbf = Qb;                          // Mt*Cd (reuse Q+K after scores)

  float* outp = (float*)d_out;              // Mt*E
  float* wts = outp + (size_t)Mt * E;       // Mt*Cd

  const int n0 = (Mt * E) / 8, n1 = (E * E) / 8;
  cvt_all<<<(n0 + 3 * n1 + 255) / 256, 256, 0, stream>>>(
      x, Wq, Wk, Wv, xb, wqb, wkb, wvb, n0, n1);

  dim3 blk(256);
  // fused QKV projection: A = xb (8192x1024), Bt = [Wq;Wk;Wv] (3072x1024)
  gemm_u3<4, 128><<<dim3(Mt / 256, 3 * E / 128, 1), blk, 0, stream>>>(
      xb, wqb, Qb, Kb, Vrow, nullptr, 3 * E, E, 0, 0, 0, Cd, 0.f, ml);
  // scores = Q K^T * scale + bias (fp32 into weights region)
  gemm_u3<2, 128><<<dim3(Cd / 256, Cd / 128, B), blk, 0, stream>>>(
      Qb, Kb, wts, nullptr, nullptr, rb, Cd, E, (long)Cd * E, (long)Cd * E,
      (long)Cd * Cd, Cd, scale, ml);
  softmax_rows<<<Mt, 256, 0, stream>>>(wts, wbf, Cd);
  // V -> V^T (xb region is dead now)
  transpose_v<<<dim3(Cd / 64, E / 64, B), 256, 0, stream>>>(Vrow, Vt, Cd, E);
  // out = weights @ V (A = bf16 weights, Bt = V^T); BN=64 -> 512 blocks, 2/CU
  gemm_u3<3, 64><<<dim3(Cd / 256, E / 64, B), blk, 0, stream>>>(
      wbf, Vt, outp, nullptr, nullptr, nullptr, E, Cd, (long)Cd * Cd,
      (long)E * Cd, (long)Cd * E, Cd, 0.f, ml);
}

// Round 15
// 199.714 us; speedup vs baseline: 1.2417x; 1.2417x over previous
//
#include <hip/hip_runtime.h>
#include <hip/hip_bf16.h>
#include <math.h>

typedef __attribute__((ext_vector_type(8))) short short8;
typedef __attribute__((ext_vector_type(4))) short short4v;
typedef __attribute__((ext_vector_type(4))) float f32x4;

static __device__ __forceinline__ short f2bf(float f) {
  union { float f; unsigned u; } x;
  x.f = f;
  unsigned r = x.u + 0x7fffu + ((x.u >> 16) & 1u);
  return (short)(r >> 16);
}

#define GLD16(g, l)                                                   \
  __builtin_amdgcn_global_load_lds(                                   \
      (const __attribute__((address_space(1))) void*)(g),             \
      (__attribute__((address_space(3))) void*)(l), 16, 0, 0)
#define BAR() asm volatile("s_barrier" ::: "memory")
#define VMCNT0() asm volatile("s_waitcnt vmcnt(0)" ::: "memory")

// fused cast: x, Wq, Wk, Wv -> bf16 in one launch
__global__ __launch_bounds__(256) void cvt_all(
    const float* __restrict__ x, const float* __restrict__ wq,
    const float* __restrict__ wk, const float* __restrict__ wv,
    short* __restrict__ xb, short* __restrict__ wqb,
    short* __restrict__ wkb, short* __restrict__ wvb, int n0, int n1) {
  int i = blockIdx.x * 256 + threadIdx.x;
  const float* src; short* dst; int off;
  if (i < n0) { src = x; dst = xb; off = i; }
  else if (i < n0 + n1) { src = wq; dst = wqb; off = i - n0; }
  else if (i < n0 + 2 * n1) { src = wk; dst = wkb; off = i - n0 - n1; }
  else if (i < n0 + 3 * n1) { src = wv; dst = wvb; off = i - n0 - 2 * n1; }
  else return;
  const float4* p = (const float4*)src + (size_t)off * 2;
  float4 a = p[0], b = p[1];
  short8 o;
  o[0] = f2bf(a.x); o[1] = f2bf(a.y); o[2] = f2bf(a.z); o[3] = f2bf(a.w);
  o[4] = f2bf(b.x); o[5] = f2bf(b.y); o[6] = f2bf(b.z); o[7] = f2bf(b.w);
  *((short8*)dst + off) = o;
}

// ---------------------------------------------------------------------------
// C = A * B^T, bf16 MFMA 16x16x32. BM=256, BN={128,64}, BK=32, 256 threads =
// 4 waves stacked in M; wave tile 64xBN. EXACT R13 structure (measured best:
// 194 us, QKV 64 us @ 33% MfmaUtil, no spill at VGPR 120): TRIPLE-buffered
// LDS, rotating pointers (NOT unrolled -- R14's x3 unroll spilled: WRITE 49->
// 142 MB scratch traffic), one vmcnt(LPT) + one barrier per K-tile, distance-2
// prefetch, both-sides XOR swizzle (slot ^= (row>>1)&3), bijective XCD
// swizzle. NEW vs R13: BN is a template param; PV uses BN=64 -> grid 512
// blocks = 2 blocks/CU (R13 PV ran 256 blocks = 1/CU, half the slots idle).
// MODE 2: C fp32 = acc*scale + rel_bias[gc-gr+ml-1] (scores)
// MODE 3: C fp32 = acc (PV)
// MODE 4: fused QKV: 1024-col slice 0 -> Q, 1 -> K, 2 -> V (ALL row-major)
// ---------------------------------------------------------------------------
template <int MODE, int BN>
__global__ __launch_bounds__(256, 2) void gemm_wt(
    const short* __restrict__ A, const short* __restrict__ Bt,
    void* __restrict__ C0, void* __restrict__ C1, void* __restrict__ C2,
    const float* __restrict__ rel_bias,
    int N, int K, long aZ, long bZ, long cZ, int Cdim, float scale, int ml) {
  constexpr int NREP = BN / 16;   // 8 or 4
  constexpr int BCH = BN / 64;    // B 64-row staging chunks: 2 or 1
  __shared__ short sA[3][256 * 32];
  __shared__ short sB[3][BN * 32];
  const int tid = threadIdx.x, lane = tid & 63, wid = tid >> 6;

  // bijective XCD swizzle over the flat workgroup id
  const int gx = gridDim.x, gy = gridDim.y;
  const int nwg = gx * gy * (int)gridDim.z;
  const int f = ((int)blockIdx.z * gy + (int)blockIdx.y) * gx + (int)blockIdx.x;
  const int qq = nwg >> 3, rr = nwg & 7;
  const int xcd = f & 7, pos = f >> 3;
  const int lg = (xcd < rr ? xcd * (qq + 1) : rr * (qq + 1) + (xcd - rr) * qq) + pos;
  const int z = lg / (gx * gy);
  const int rem = lg - z * (gx * gy);
  const int bx = rem / gy, by = rem - bx * gy;  // by fastest: A-panel reuse

  const short* Az = A + (size_t)z * aZ;
  const short* Bz = Bt + (size_t)z * bZ;
  const int brow = bx * 256, bcol = by * BN;
  const int lrow = lane & 15, kg = lane >> 4;

  // staging: chunk c covers rows c*64..+63; thread -> row tid>>2, slot tid&3
  const int t4 = tid >> 2;
  const int logslot = (tid & 3) ^ ((tid >> 3) & 3);  // pre-swizzled src slot
  const short* aSrc[4];
#pragma unroll
  for (int c = 0; c < 4; ++c)
    aSrc[c] = Az + (size_t)(brow + c * 64 + t4) * K + logslot * 8;
  const short* bSrc[BCH];
#pragma unroll
  for (int c = 0; c < BCH; ++c)
    bSrc[c] = Bz + (size_t)(bcol + c * 64 + t4) * K + logslot * 8;
  const int dW = wid * 512;  // wave-uniform LDS dest offset within chunk

  // ds_read: physical slot = kg ^ ((row>>1)&3); (row>>1)&3 == (lrow>>1)&3
  const int kOff = (kg ^ ((lrow >> 1) & 3)) * 8;
  const int aBase = (wid * 64 + lrow) * 32 + kOff;  // + m*512
  const int bBase = lrow * 32 + kOff;               // + n*512

  short8 a[4], b[NREP];
  f32x4 acc[4][NREP] = {};

  short *pa0 = &sA[0][0], *pa1 = &sA[1][0], *pa2 = &sA[2][0];
  short *pb0 = &sB[0][0], *pb1 = &sB[1][0], *pb2 = &sB[2][0];

#define STG(PA, PB, T)                                               \
  do {                                                               \
    GLD16(aSrc[0] + (size_t)(T) * 32, (PA) + 0 * 2048 + dW);         \
    GLD16(aSrc[1] + (size_t)(T) * 32, (PA) + 1 * 2048 + dW);         \
    GLD16(aSrc[2] + (size_t)(T) * 32, (PA) + 2 * 2048 + dW);         \
    GLD16(aSrc[3] + (size_t)(T) * 32, (PA) + 3 * 2048 + dW);         \
    GLD16(bSrc[0] + (size_t)(T) * 32, (PB) + 0 * 2048 + dW);         \
    if constexpr (BCH == 2)                                          \
      GLD16(bSrc[1] + (size_t)(T) * 32, (PB) + 2048 + dW);           \
  } while (0)
#define RD(PA, PB)                                                  \
  do {                                                              \
    _Pragma("unroll") for (int m = 0; m < 4; ++m)                   \
        a[m] = *(const short8*)&(PA)[aBase + m * 512];              \
    _Pragma("unroll") for (int n = 0; n < NREP; ++n)                \
        b[n] = *(const short8*)&(PB)[bBase + n * 512];              \
  } while (0)
#define MFMA_ALL()                                                            \
  do {                                                                        \
    __builtin_amdgcn_s_setprio(1);                                            \
    _Pragma("unroll") for (int m = 0; m < 4; ++m)                             \
        _Pragma("unroll") for (int n = 0; n < NREP; ++n)                      \
            acc[m][n] = __builtin_amdgcn_mfma_f32_16x16x32_bf16(              \
                a[m], b[n], acc[m][n], 0, 0, 0);                              \
    __builtin_amdgcn_s_setprio(0);                                            \
  } while (0)
#define VM_LPT()                                                    \
  do {                                                              \
    if constexpr (BCH == 2)                                         \
      asm volatile("s_waitcnt vmcnt(6)" ::: "memory");              \
    else                                                            \
      asm volatile("s_waitcnt vmcnt(5)" ::: "memory");              \
  } while (0)
#define ROT()                                                    \
  do {                                                           \
    short* q;                                                    \
    q = pa0; pa0 = pa1; pa1 = pa2; pa2 = q;                      \
    q = pb0; pb0 = pb1; pb1 = pb2; pb2 = q;                      \
  } while (0)

  // prologue: tiles 0,1 staged (2*LPT loads outstanding)
  STG(pa0, pb0, 0);
  STG(pa1, pb1, 1);

  const int NT = K >> 5;  // K/32 tiles (32 or 64 here)
  for (int t = 0; t < NT - 2; ++t) {
    VM_LPT();   // drain tile t (tile t+1's LPT stay in flight)
    BAR();
    RD(pa0, pb0);
    STG(pa2, pb2, t + 2);   // buf freed by iter t-1's reads (pre-barrier)
    MFMA_ALL();
    ROT();
  }
  // t = NT-2: no staging
  VM_LPT();
  BAR();
  RD(pa0, pb0);
  MFMA_ALL();
  ROT();
  // t = NT-1
  VMCNT0();
  BAR();
  RD(pa0, pb0);
  MFMA_ALL();

  // epilogue
#pragma unroll
  for (int m = 0; m < 4; ++m) {
#pragma unroll
    for (int n = 0; n < NREP; ++n) {
#pragma unroll
      for (int r = 0; r < 4; ++r) {
        float v = acc[m][n][r];
        int gr = brow + wid * 64 + m * 16 + kg * 4 + r;
        int gc = bcol + n * 16 + lrow;
        if constexpr (MODE == 2) {
          int idx = gc - gr + (ml - 1);
          idx = min(max(idx, 0), 2 * ml - 2);
          ((float*)C0 + (size_t)z * cZ)[(size_t)gr * N + gc] =
              v * scale + rel_bias[idx];
        } else if constexpr (MODE == 3) {
          ((float*)C0 + (size_t)z * cZ)[(size_t)gr * N + gc] = v;
        } else {  // MODE 4: fused QKV, 1024-col slices, ALL row-major
          int s = gc >> 10, cc = gc & 1023;
          short* dst = (s == 0) ? (short*)C0 : (s == 1) ? (short*)C1 : (short*)C2;
          dst[(size_t)gr * 1024 + cc] = f2bf(v);
        }
      }
    }
  }
#undef STG
#undef RD
#undef MFMA_ALL
#undef VM_LPT
#undef ROT
}

// 64x64 LDS tile transpose: vin[b][c][e] (row-major [Cd][E]) -> vout[b][e][c]
__global__ __launch_bounds__(256) void transpose_v(const short* __restrict__ vin,
                                                   short* __restrict__ vout,
                                                   int Cd, int E) {
  __shared__ short t[64][72];
  const int c0 = blockIdx.x * 64, e0 = blockIdx.y * 64, b = blockIdx.z;
  const int tid = threadIdx.x;
  const int cr = tid >> 2;             // 0..63: input row within tile
  const int ec = (tid & 3) * 16;       // input col chunk
  const short* src = vin + ((size_t)b * Cd + c0 + cr) * E + e0 + ec;
  short8 v0 = *(const short8*)src;
  short8 v1 = *(const short8*)(src + 8);
#pragma unroll
  for (int j = 0; j < 8; ++j) t[ec + j][cr] = v0[j];
#pragma unroll
  for (int j = 0; j < 8; ++j) t[ec + 8 + j][cr] = v1[j];
  __syncthreads();
  const int er = tid >> 2;             // output row (e-dim)
  const int cc = (tid & 3) * 16;       // output col chunk (c-dim)
  short* dst = vout + ((size_t)b * E + e0 + er) * Cd + c0 + cc;
  *(short8*)dst = *(const short8*)&t[er][cc];
  *(short8*)(dst + 8) = *(const short8*)&t[er][cc + 8];
}

// Row softmax in place (rows of 2048) + bf16 copy for the PV GEMM.
__global__ __launch_bounds__(256) void softmax_rows(float* __restrict__ w,
                                                    short* __restrict__ wb, int Cd) {
  const size_t row = blockIdx.x;
  float4* p = (float4*)(w + row * (size_t)Cd);
  const int tid = threadIdx.x;
  float4 v0 = p[tid];
  float4 v1 = p[tid + 256];
  float mx = fmaxf(fmaxf(fmaxf(v0.x, v0.y), fmaxf(v0.z, v0.w)),
                   fmaxf(fmaxf(v1.x, v1.y), fmaxf(v1.z, v1.w)));
#pragma unroll
  for (int o = 32; o; o >>= 1) mx = fmaxf(mx, __shfl_xor(mx, o));
  __shared__ float red[8];
  const int wv = tid >> 6;
  if ((tid & 63) == 0) red[wv] = mx;
  __syncthreads();
  mx = fmaxf(fmaxf(red[0], red[1]), fmaxf(red[2], red[3]));
  v0.x = __expf(v0.x - mx); v0.y = __expf(v0.y - mx);
  v0.z = __expf(v0.z - mx); v0.w = __expf(v0.w - mx);
  v1.x = __expf(v1.x - mx); v1.y = __expf(v1.y - mx);
  v1.z = __expf(v1.z - mx); v1.w = __expf(v1.w - mx);
  float s = v0.x + v0.y + v0.z + v0.w + v1.x + v1.y + v1.z + v1.w;
#pragma unroll
  for (int o = 32; o; o >>= 1) s += __shfl_xor(s, o);
  if ((tid & 63) == 0) red[4 + wv] = s;
  __syncthreads();
  s = red[4] + red[5] + red[6] + red[7];
  float inv = 1.0f / s;
  v0.x *= inv; v0.y *= inv; v0.z *= inv; v0.w *= inv;
  v1.x *= inv; v1.y *= inv; v1.z *= inv; v1.w *= inv;
  p[tid] = v0;
  p[tid + 256] = v1;
  short4v b0, b1;
  b0[0] = f2bf(v0.x); b0[1] = f2bf(v0.y); b0[2] = f2bf(v0.z); b0[3] = f2bf(v0.w);
  b1[0] = f2bf(v1.x); b1[1] = f2bf(v1.y); b1[2] = f2bf(v1.z); b1[3] = f2bf(v1.w);
  short* wrow = wb + row * (size_t)Cd;
  *(short4v*)&wrow[tid * 4] = b0;
  *(short4v*)&wrow[1024 + tid * 4] = b1;
}

extern "C" void kernel_launch(void* const* d_in, const int* in_sizes, int n_in,
                              void* d_out, int out_size, void* d_ws, size_t ws_size,
                              hipStream_t stream) {
  const float* x = (const float*)d_in[0];
  const float* Wq = (const float*)d_in[1];
  const float* Wk = (const float*)d_in[2];
  const float* Wv = (const float*)d_in[3];
  const float* rb = (const float*)d_in[4];

  const int E = 1024;
  const int Mt = in_sizes[0] / E;           // B*C = 8192
  const int Cd = out_size / Mt - E;         // 2048
  const int B = Mt / Cd;                    // 4
  const int ml = (in_sizes[4] + 1) / 2;     // max_len = 2048
  const float scale = 1.0f / sqrtf((float)E);

  // workspace layout (bf16 = short), 70 MB
  short* xb = (short*)d_ws;                 // Mt*E (dead after QKV -> Vt)
  short* wqb = xb + (size_t)Mt * E;         // E*E x3
  short* wkb = wqb + (size_t)E * E;
  short* wvb = wkb + (size_t)E * E;
  short* Qb = wvb + (size_t)E * E;          // Mt*E
  short* Kb = Qb + (size_t)Mt * E;          // Mt*E
  short* Vrow = Kb + (size_t)Mt * E;        // Mt*E (V row-major)
  short* Vt = xb;                           // B*E*Cd = Mt*E (reuse xb)
  short* wbf = Qb;                          // Mt*Cd (reuse Q+K after scores)

  float* outp = (float*)d_out;              // Mt*E
  float* wts = outp + (size_t)Mt * E;       // Mt*Cd

  const int n0 = (Mt * E) / 8, n1 = (E * E) / 8;
  cvt_all<<<(n0 + 3 * n1 + 255) / 256, 256, 0, stream>>>(
      x, Wq, Wk, Wv, xb, wqb, wkb, wvb, n0, n1);

  dim3 blk(256);
  // fused QKV projection: A = xb (8192x1024), Bt = [Wq;Wk;Wv] (3072x1024)
  gemm_wt<4, 128><<<dim3(Mt / 256, 3 * E / 128, 1), blk, 0, stream>>>(
      xb, wqb, Qb, Kb, Vrow, nullptr, 3 * E, E, 0, 0, 0, Cd, 0.f, ml);
  // scores = Q K^T * scale + bias (fp32 into weights region)
  gemm_wt<2, 128><<<dim3(Cd / 256, Cd / 128, B), blk, 0, stream>>>(
      Qb, Kb, wts, nullptr, nullptr, rb, Cd, E, (long)Cd * E, (long)Cd * E,
      (long)Cd * Cd, Cd, scale, ml);
  softmax_rows<<<Mt, 256, 0, stream>>>(wts, wbf, Cd);
  // V -> V^T (xb region is dead now)
  transpose_v<<<dim3(Cd / 64, E / 64, B), 256, 0, stream>>>(Vrow, Vt, Cd, E);
  // out = weights @ V (A = bf16 weights, Bt = V^T); BN=64 -> 512 blocks, 2/CU
  gemm_wt<3, 64><<<dim3(Cd / 256, E / 64, B), blk, 0, stream>>>(
      wbf, Vt, outp, nullptr, nullptr, nullptr, E, Cd, (long)Cd * Cd,
      (long)E * Cd, (long)Cd * E, Cd, 0.f, ml);
}

// Round 16
// 193.776 us; speedup vs baseline: 1.2798x; 1.0306x over previous
//
#include <hip/hip_runtime.h>
#include <hip/hip_bf16.h>
#include <math.h>

typedef __attribute__((ext_vector_type(8))) short short8;
typedef __attribute__((ext_vector_type(4))) short short4v;
typedef __attribute__((ext_vector_type(4))) float f32x4;

static __device__ __forceinline__ short f2bf(float f) {
  union { float f; unsigned u; } x;
  x.f = f;
  unsigned r = x.u + 0x7fffu + ((x.u >> 16) & 1u);
  return (short)(r >> 16);
}

#define GLD16(g, l)                                                   \
  __builtin_amdgcn_global_load_lds(                                   \
      (const __attribute__((address_space(1))) void*)(g),             \
      (__attribute__((address_space(3))) void*)(l), 16, 0, 0)
#define BAR() asm volatile("s_barrier" ::: "memory")
#define VMCNT6() asm volatile("s_waitcnt vmcnt(6)" ::: "memory")
#define VMCNT0() asm volatile("s_waitcnt vmcnt(0)" ::: "memory")

// fused cast: x, Wq, Wk, Wv -> bf16 in one launch
__global__ __launch_bounds__(256) void cvt_all(
    const float* __restrict__ x, const float* __restrict__ wq,
    const float* __restrict__ wk, const float* __restrict__ wv,
    short* __restrict__ xb, short* __restrict__ wqb,
    short* __restrict__ wkb, short* __restrict__ wvb, int n0, int n1) {
  int i = blockIdx.x * 256 + threadIdx.x;
  const float* src; short* dst; int off;
  if (i < n0) { src = x; dst = xb; off = i; }
  else if (i < n0 + n1) { src = wq; dst = wqb; off = i - n0; }
  else if (i < n0 + 2 * n1) { src = wk; dst = wkb; off = i - n0 - n1; }
  else if (i < n0 + 3 * n1) { src = wv; dst = wvb; off = i - n0 - 2 * n1; }
  else return;
  const float4* p = (const float4*)src + (size_t)off * 2;
  float4 a = p[0], b = p[1];
  short8 o;
  o[0] = f2bf(a.x); o[1] = f2bf(a.y); o[2] = f2bf(a.z); o[3] = f2bf(a.w);
  o[4] = f2bf(b.x); o[5] = f2bf(b.y); o[6] = f2bf(b.z); o[7] = f2bf(b.w);
  *((short8*)dst + off) = o;
}

// ---------------------------------------------------------------------------
// C = A * B^T, bf16 MFMA 16x16x32. BM=256, BN=128, BK=32, 256 threads =
// 4 waves stacked in M; wave tile 64x128 (M_rep=4, N_rep=8). MEASURED BEST
// (R13: 194 us total; QKV 64 us @ 33% MfmaUtil, VGPR 120, no spill).
// TRIPLE-buffered LDS (72 KB -> 2 blocks/CU), rotating buffer pointers
// (R14's x3 unroll spilled: scratch WRITE 49->142 MB), one vmcnt(6) + one
// barrier per K-tile, distance-2 prefetch, both-sides XOR swizzle
// (slot ^= (row>>1)&3), bijective XCD block swizzle. PV stays BN=128
// (R15's BN=64 regressed: wave tile 64x64 FLOP/LDS-byte 42.7->32 and 2x
// A-panel re-fetch; R11 proved occupancy isn't the binding constraint).
// MODE 2: C fp32 = acc*scale + rel_bias[gc-gr+ml-1] (scores)
// MODE 3: C fp32 = acc (PV)
// MODE 4: fused QKV: 1024-col slice 0 -> Q, 1 -> K, 2 -> V (ALL row-major)
// ---------------------------------------------------------------------------
template <int MODE>
__global__ __launch_bounds__(256, 2) void gemm_wt(
    const short* __restrict__ A, const short* __restrict__ Bt,
    void* __restrict__ C0, void* __restrict__ C1, void* __restrict__ C2,
    const float* __restrict__ rel_bias,
    int N, int K, long aZ, long bZ, long cZ, int Cdim, float scale, int ml) {
  __shared__ short sA[3][256 * 32];
  __shared__ short sB[3][128 * 32];
  const int tid = threadIdx.x, lane = tid & 63, wid = tid >> 6;

  // bijective XCD swizzle over the flat workgroup id
  const int gx = gridDim.x, gy = gridDim.y;
  const int nwg = gx * gy * (int)gridDim.z;
  const int f = ((int)blockIdx.z * gy + (int)blockIdx.y) * gx + (int)blockIdx.x;
  const int qq = nwg >> 3, rr = nwg & 7;
  const int xcd = f & 7, pos = f >> 3;
  const int lg = (xcd < rr ? xcd * (qq + 1) : rr * (qq + 1) + (xcd - rr) * qq) + pos;
  const int z = lg / (gx * gy);
  const int rem = lg - z * (gx * gy);
  const int bx = rem / gy, by = rem - bx * gy;  // by fastest: A-panel reuse

  const short* Az = A + (size_t)z * aZ;
  const short* Bz = Bt + (size_t)z * bZ;
  const int brow = bx * 256, bcol = by * 128;
  const int lrow = lane & 15, kg = lane >> 4;

  // staging: chunk c covers rows c*64..+63; thread -> row tid>>2, slot tid&3
  const int t4 = tid >> 2;
  const int logslot = (tid & 3) ^ ((tid >> 3) & 3);  // pre-swizzled src slot
  const short* aSrc[4];
#pragma unroll
  for (int c = 0; c < 4; ++c)
    aSrc[c] = Az + (size_t)(brow + c * 64 + t4) * K + logslot * 8;
  const short* bSrc[2];
#pragma unroll
  for (int c = 0; c < 2; ++c)
    bSrc[c] = Bz + (size_t)(bcol + c * 64 + t4) * K + logslot * 8;
  const int dW = wid * 512;  // wave-uniform LDS dest offset within chunk

  // ds_read: physical slot = kg ^ ((row>>1)&3); (row>>1)&3 == (lrow>>1)&3
  const int kOff = (kg ^ ((lrow >> 1) & 3)) * 8;
  const int aBase = (wid * 64 + lrow) * 32 + kOff;  // + m*512
  const int bBase = lrow * 32 + kOff;               // + n*512

  short8 a[4], b[8];
  f32x4 acc[4][8] = {};

  short *pa0 = &sA[0][0], *pa1 = &sA[1][0], *pa2 = &sA[2][0];
  short *pb0 = &sB[0][0], *pb1 = &sB[1][0], *pb2 = &sB[2][0];

#define STG(PA, PB, T)                                               \
  do {                                                               \
    GLD16(aSrc[0] + (size_t)(T) * 32, (PA) + 0 * 2048 + dW);         \
    GLD16(aSrc[1] + (size_t)(T) * 32, (PA) + 1 * 2048 + dW);         \
    GLD16(aSrc[2] + (size_t)(T) * 32, (PA) + 2 * 2048 + dW);         \
    GLD16(aSrc[3] + (size_t)(T) * 32, (PA) + 3 * 2048 + dW);         \
    GLD16(bSrc[0] + (size_t)(T) * 32, (PB) + 0 * 2048 + dW);         \
    GLD16(bSrc[1] + (size_t)(T) * 32, (PB) + 1 * 2048 + dW);         \
  } while (0)
#define RD(PA, PB)                                                  \
  do {                                                              \
    _Pragma("unroll") for (int m = 0; m < 4; ++m)                   \
        a[m] = *(const short8*)&(PA)[aBase + m * 512];              \
    _Pragma("unroll") for (int n = 0; n < 8; ++n)                   \
        b[n] = *(const short8*)&(PB)[bBase + n * 512];              \
  } while (0)
#define MFMA32()                                                              \
  do {                                                                        \
    __builtin_amdgcn_s_setprio(1);                                            \
    _Pragma("unroll") for (int m = 0; m < 4; ++m)                             \
        _Pragma("unroll") for (int n = 0; n < 8; ++n)                         \
            acc[m][n] = __builtin_amdgcn_mfma_f32_16x16x32_bf16(              \
                a[m], b[n], acc[m][n], 0, 0, 0);                              \
    __builtin_amdgcn_s_setprio(0);                                            \
  } while (0)
#define ROT()                                                    \
  do {                                                           \
    short* q;                                                    \
    q = pa0; pa0 = pa1; pa1 = pa2; pa2 = q;                      \
    q = pb0; pb0 = pb1; pb1 = pb2; pb2 = q;                      \
  } while (0)

  // prologue: tiles 0,1 staged (12 loads outstanding)
  STG(pa0, pb0, 0);
  STG(pa1, pb1, 1);

  const int NT = K >> 5;  // K/32 tiles (32 or 64 here)
  for (int t = 0; t < NT - 2; ++t) {
    VMCNT6();   // drain tile t (tile t+1's 6 stay in flight)
    BAR();
    RD(pa0, pb0);
    STG(pa2, pb2, t + 2);   // buf freed by iter t-1's reads (pre-barrier)
    MFMA32();
    ROT();
  }
  // t = NT-2: no staging
  VMCNT6();
  BAR();
  RD(pa0, pb0);
  MFMA32();
  ROT();
  // t = NT-1
  VMCNT0();
  BAR();
  RD(pa0, pb0);
  MFMA32();

  // epilogue
#pragma unroll
  for (int m = 0; m < 4; ++m) {
#pragma unroll
    for (int n = 0; n < 8; ++n) {
#pragma unroll
      for (int r = 0; r < 4; ++r) {
        float v = acc[m][n][r];
        int gr = brow + wid * 64 + m * 16 + kg * 4 + r;
        int gc = bcol + n * 16 + lrow;
        if constexpr (MODE == 2) {
          int idx = gc - gr + (ml - 1);
          idx = min(max(idx, 0), 2 * ml - 2);
          ((float*)C0 + (size_t)z * cZ)[(size_t)gr * N + gc] =
              v * scale + rel_bias[idx];
        } else if constexpr (MODE == 3) {
          ((float*)C0 + (size_t)z * cZ)[(size_t)gr * N + gc] = v;
        } else {  // MODE 4: fused QKV, 1024-col slices, ALL row-major
          int s = gc >> 10, cc = gc & 1023;
          short* dst = (s == 0) ? (short*)C0 : (s == 1) ? (short*)C1 : (short*)C2;
          dst[(size_t)gr * 1024 + cc] = f2bf(v);
        }
      }
    }
  }
#undef STG
#undef RD
#undef MFMA32
#undef ROT
}

// 64x64 LDS tile transpose: vin[b][c][e] (row-major [Cd][E]) -> vout[b][e][c]
__global__ __launch_bounds__(256) void transpose_v(const short* __restrict__ vin,
                                                   short* __restrict__ vout,
                                                   int Cd, int E) {
  __shared__ short t[64][72];
  const int c0 = blockIdx.x * 64, e0 = blockIdx.y * 64, b = blockIdx.z;
  const int tid = threadIdx.x;
  const int cr = tid >> 2;             // 0..63: input row within tile
  const int ec = (tid & 3) * 16;       // input col chunk
  const short* src = vin + ((size_t)b * Cd + c0 + cr) * E + e0 + ec;
  short8 v0 = *(const short8*)src;
  short8 v1 = *(const short8*)(src + 8);
#pragma unroll
  for (int j = 0; j < 8; ++j) t[ec + j][cr] = v0[j];
#pragma unroll
  for (int j = 0; j < 8; ++j) t[ec + 8 + j][cr] = v1[j];
  __syncthreads();
  const int er = tid >> 2;             // output row (e-dim)
  const int cc = (tid & 3) * 16;       // output col chunk (c-dim)
  short* dst = vout + ((size_t)b * E + e0 + er) * Cd + c0 + cc;
  *(short8*)dst = *(const short8*)&t[er][cc];
  *(short8*)(dst + 8) = *(const short8*)&t[er][cc + 8];
}

// Row softmax in place (rows of 2048) + bf16 copy for the PV GEMM.
__global__ __launch_bounds__(256) void softmax_rows(float* __restrict__ w,
                                                    short* __restrict__ wb, int Cd) {
  const size_t row = blockIdx.x;
  float4* p = (float4*)(w + row * (size_t)Cd);
  const int tid = threadIdx.x;
  float4 v0 = p[tid];
  float4 v1 = p[tid + 256];
  float mx = fmaxf(fmaxf(fmaxf(v0.x, v0.y), fmaxf(v0.z, v0.w)),
                   fmaxf(fmaxf(v1.x, v1.y), fmaxf(v1.z, v1.w)));
#pragma unroll
  for (int o = 32; o; o >>= 1) mx = fmaxf(mx, __shfl_xor(mx, o));
  __shared__ float red[8];
  const int wv = tid >> 6;
  if ((tid & 63) == 0) red[wv] = mx;
  __syncthreads();
  mx = fmaxf(fmaxf(red[0], red[1]), fmaxf(red[2], red[3]));
  v0.x = __expf(v0.x - mx); v0.y = __expf(v0.y - mx);
  v0.z = __expf(v0.z - mx); v0.w = __expf(v0.w - mx);
  v1.x = __expf(v1.x - mx); v1.y = __expf(v1.y - mx);
  v1.z = __expf(v1.z - mx); v1.w = __expf(v1.w - mx);
  float s = v0.x + v0.y + v0.z + v0.w + v1.x + v1.y + v1.z + v1.w;
#pragma unroll
  for (int o = 32; o; o >>= 1) s += __shfl_xor(s, o);
  if ((tid & 63) == 0) red[4 + wv] = s;
  __syncthreads();
  s = red[4] + red[5] + red[6] + red[7];
  float inv = 1.0f / s;
  v0.x *= inv; v0.y *= inv; v0.z *= inv; v0.w *= inv;
  v1.x *= inv; v1.y *= inv; v1.z *= inv; v1.w *= inv;
  p[tid] = v0;
  p[tid + 256] = v1;
  short4v b0, b1;
  b0[0] = f2bf(v0.x); b0[1] = f2bf(v0.y); b0[2] = f2bf(v0.z); b0[3] = f2bf(v0.w);
  b1[0] = f2bf(v1.x); b1[1] = f2bf(v1.y); b1[2] = f2bf(v1.z); b1[3] = f2bf(v1.w);
  short* wrow = wb + row * (size_t)Cd;
  *(short4v*)&wrow[tid * 4] = b0;
  *(short4v*)&wrow[1024 + tid * 4] = b1;
}

extern "C" void kernel_launch(void* const* d_in, const int* in_sizes, int n_in,
                              void* d_out, int out_size, void* d_ws, size_t ws_size,
                              hipStream_t stream) {
  const float* x = (const float*)d_in[0];
  const float* Wq = (const float*)d_in[1];
  const float* Wk = (const float*)d_in[2];
  const float* Wv = (const float*)d_in[3];
  const float* rb = (const float*)d_in[4];

  const int E = 1024;
  const int Mt = in_sizes[0] / E;           // B*C = 8192
  const int Cd = out_size / Mt - E;         // 2048
  const int B = Mt / Cd;                    // 4
  const int ml = (in_sizes[4] + 1) / 2;     // max_len = 2048
  const float scale = 1.0f / sqrtf((float)E);

  // workspace layout (bf16 = short), 70 MB
  short* xb = (short*)d_ws;                 // Mt*E (dead after QKV -> Vt)
  short* wqb = xb + (size_t)Mt * E;         // E*E x3
  short* wkb = wqb + (size_t)E * E;
  short* wvb = wkb + (size_t)E * E;
  short* Qb = wvb + (size_t)E * E;          // Mt*E
  short* Kb = Qb + (size_t)Mt * E;          // Mt*E
  short* Vrow = Kb + (size_t)Mt * E;        // Mt*E (V row-major)
  short* Vt = xb;                           // B*E*Cd = Mt*E (reuse xb)
  short* wbf = Qb;                          // Mt*Cd (reuse Q+K after scores)

  float* outp = (float*)d_out;              // Mt*E
  float* wts = outp + (size_t)Mt * E;       // Mt*Cd

  const int n0 = (Mt * E) / 8, n1 = (E * E) / 8;
  cvt_all<<<(n0 + 3 * n1 + 255) / 256, 256, 0, stream>>>(
      x, Wq, Wk, Wv, xb, wqb, wkb, wvb, n0, n1);

  dim3 blk(256);
  // fused QKV projection: A = xb (8192x1024), Bt = [Wq;Wk;Wv] (3072x1024)
  gemm_wt<4><<<dim3(Mt / 256, 3 * E / 128, 1), blk, 0, stream>>>(
      xb, wqb, Qb, Kb, Vrow, nullptr, 3 * E, E, 0, 0, 0, Cd, 0.f, ml);
  // scores = Q K^T * scale + bias (fp32 into weights region)
  gemm_wt<2><<<dim3(Cd / 256, Cd / 128, B), blk, 0, stream>>>(
      Qb, Kb, wts, nullptr, nullptr, rb, Cd, E, (long)Cd * E, (long)Cd * E,
      (long)Cd * Cd, Cd, scale, ml);
  softmax_rows<<<Mt, 256, 0, stream>>>(wts, wbf, Cd);
  // V -> V^T (xb region is dead now)
  transpose_v<<<dim3(Cd / 64, E / 64, B), 256, 0, stream>>>(Vrow, Vt, Cd, E);
  // out = weights @ V (A = bf16 weights, Bt = V^T)
  gemm_wt<3><<<dim3(Cd / 256, E / 128, B), blk, 0, stream>>>(
      wbf, Vt, outp, nullptr, nullptr, nullptr, E, Cd, (long)Cd * Cd,
      (long)E * Cd, (long)Cd * E, Cd, 0.f, ml);
}